// Round 2
// baseline (209.922 us; speedup 1.0000x reference)
//
#include <hip/hip_runtime.h>
#include <math.h>

namespace {
constexpr int Kc   = 64;     // K
constexpr int SP1  = 5;      // S+1
constexpr int Mm   = Kc * SP1;          // 320
constexpr int DIM  = 128;
constexpr int Nn   = 16;
constexpr int Pp   = 1200;              // 30*40
constexpr int PT   = 64;                // pixels per tile
constexpr int NT   = (Pp + PT - 1) / PT;  // 19
constexpr int WAVES = 8;
constexpr int TPB2 = WAVES * 64;        // 512
constexpr int KPW  = Kc / WAVES;        // 8 k-values per wave
}

// ---------------------------------------------------------------- k_bias ----
__global__ void k_bias(const float* __restrict__ cent, float* __restrict__ b) {
  int m = blockIdx.x * 64 + threadIdx.x;
  if (m < Mm) {
    const float* r = cent + (size_t)m * DIM;
    float s = 0.f;
    #pragma unroll
    for (int c = 0; c < DIM; ++c) s = fmaf(r[c], r[c], s);
    b[m] = -100.0f * sqrtf(s);   // -ALPHA * ||c||
  }
}

// ---------------------------------------------------------------- k_mult ----
// Block: 512 threads = 8 waves; lane = pixel (64/tile), wave w owns k in
// [w*8, w*8+8). conv values live in registers; only cross-wave softmax
// stats (M1/Z1 over k, per (s,pixel)) go through LDS.
__global__ __launch_bounds__(TPB2, 2) void k_mult(
    const float* __restrict__ x, const float* __restrict__ cent,
    const float* __restrict__ b, float* __restrict__ mult_g,
    float* __restrict__ S_part) {
  const int tile = blockIdx.x, n = blockIdx.y;
  const int p0   = tile * PT;
  const int lane = threadIdx.x & 63;
  const int w    = threadIdx.x >> 6;
  const int cnt  = min(PT, Pp - p0);
  const bool act = lane < cnt;

  __shared__ float m1part[WAVES][SP1][PT];
  __shared__ float z1part[WAVES][SP1][PT];
  __shared__ float m1f[SP1][PT];
  __shared__ float z1f[SP1][PT];

  // x[n,:,p] into registers (coalesced: lanes contiguous in p)
  float xr[DIM];
  {
    const float* xp = x + ((size_t)n * DIM) * Pp + p0 + lane;
    #pragma unroll
    for (int c = 0; c < DIM; ++c) xr[c] = act ? xp[(size_t)c * Pp] : 0.f;
  }

  float cv[KPW][SP1];          // conv values, registers (all loops unrolled!)
  float m1loc[SP1];
  #pragma unroll
  for (int s = 0; s < SP1; ++s) m1loc[s] = -3.4e38f;

  #pragma unroll
  for (int kk = 0; kk < KPW; ++kk) {
    const int k = __builtin_amdgcn_readfirstlane(w * KPW + kk);  // uniform -> s_load
    const float* wr = cent + (size_t)k * SP1 * DIM;
    float a0 = 0.f, a1 = 0.f, a2 = 0.f, a3 = 0.f, a4 = 0.f;
    #pragma unroll
    for (int c = 0; c < DIM; ++c) {
      const float xv = xr[c];
      a0 = fmaf(wr[c],         xv, a0);
      a1 = fmaf(wr[DIM + c],   xv, a1);
      a2 = fmaf(wr[2*DIM + c], xv, a2);
      a3 = fmaf(wr[3*DIM + c], xv, a3);
      a4 = fmaf(wr[4*DIM + c], xv, a4);
    }
    const float t[SP1] = {a0, a1, a2, a3, a4};
    #pragma unroll
    for (int s = 0; s < SP1; ++s) {
      const float v = fmaf(200.0f, t[s], b[k * SP1 + s]);  // 2*ALPHA*dot + bias
      cv[kk][s] = v;
      m1loc[s] = fmaxf(m1loc[s], v);
    }
  }
  #pragma unroll
  for (int s = 0; s < SP1; ++s) m1part[w][s][lane] = m1loc[s];
  __syncthreads();
  // reduce M1 (max over k) across waves
  for (int i = threadIdx.x; i < SP1 * PT; i += TPB2) {
    const int s = i >> 6, l = i & 63;
    float m = m1part[0][s][l];
    #pragma unroll
    for (int ww = 1; ww < WAVES; ++ww) m = fmaxf(m, m1part[ww][s][l]);
    m1f[s][l] = m;
  }
  __syncthreads();
  float m1r[SP1];
  #pragma unroll
  for (int s = 0; s < SP1; ++s) m1r[s] = m1f[s][lane];
  // Z1 partials: sum_k exp(conv - M1[s])
  float z1loc[SP1] = {0.f, 0.f, 0.f, 0.f, 0.f};
  #pragma unroll
  for (int kk = 0; kk < KPW; ++kk) {
    #pragma unroll
    for (int s = 0; s < SP1; ++s) z1loc[s] += expf(cv[kk][s] - m1r[s]);
  }
  #pragma unroll
  for (int s = 0; s < SP1; ++s) z1part[w][s][lane] = z1loc[s];
  __syncthreads();
  for (int i = threadIdx.x; i < SP1 * PT; i += TPB2) {
    const int s = i >> 6, l = i & 63;
    float z = z1part[0][s][l];
    #pragma unroll
    for (int ww = 1; ww < WAVES; ++ww) z += z1part[ww][s][l];
    z1f[s][l] = z;
  }
  __syncthreads();
  float z1r[SP1];
  #pragma unroll
  for (int s = 0; s < SP1; ++s) z1r[s] = z1f[s][lane];

  // mult = prod_s (1 + sm1*sm2),  sm1 = e1/Z1, sm2 = e2/Z2
  #pragma unroll
  for (int kk = 0; kk < KPW; ++kk) {
    const int k = w * KPW + kk;
    float M2 = cv[kk][0];
    #pragma unroll
    for (int s = 1; s < SP1; ++s) M2 = fmaxf(M2, cv[kk][s]);
    float e2[SP1], Z2 = 0.f;
    #pragma unroll
    for (int s = 0; s < SP1; ++s) { e2[s] = expf(cv[kk][s] - M2); Z2 += e2[s]; }
    float mlt = 1.f;
    #pragma unroll
    for (int s = 0; s < SP1; ++s) {
      const float e1 = expf(cv[kk][s] - m1r[s]);
      mlt *= 1.f + (e1 / z1r[s]) * (e2[s] / Z2);
    }
    if (act) mult_g[((size_t)n * Kc + k) * Pp + p0 + lane] = mlt;
    float msum = act ? mlt : 0.f;
    #pragma unroll
    for (int off = 32; off > 0; off >>= 1) msum += __shfl_down(msum, off, 64);
    if (lane == 0) S_part[((size_t)n * NT + tile) * Kc + k] = msum;  // deterministic
  }
}

// ----------------------------------------------------------------- k_acc ----
// out_acc[n,k,c] += sum_{p in chunk} x[n,c,p] * mult[n,k,p]
__global__ __launch_bounds__(256) void k_acc(
    const float* __restrict__ x, const float* __restrict__ mult_g,
    float* __restrict__ out_acc) {
  const int chunk = blockIdx.x, n = blockIdx.y;
  const int p0  = chunk * PT;
  const int cnt = min(PT, Pp - p0);
  __shared__ float xs[DIM][PT + 1];
  __shared__ float ms[Kc][PT + 1];
  for (int i = threadIdx.x; i < DIM * PT; i += 256) {
    const int c = i >> 6, p = i & 63;
    xs[c][p] = (p < cnt) ? x[((size_t)n * DIM + c) * Pp + p0 + p] : 0.f;
  }
  for (int i = threadIdx.x; i < Kc * PT; i += 256) {
    const int k = i >> 6, p = i & 63;
    ms[k][p] = (p < cnt) ? mult_g[((size_t)n * Kc + k) * Pp + p0 + p] : 0.f;
  }
  __syncthreads();
  // thread -> c = cg+16j (16-consecutive-bank reads), k = kg+16i (broadcast)
  const int cg = threadIdx.x & 15;
  const int kg = threadIdx.x >> 4;
  float acc[4][8] = {};
  for (int p = 0; p < PT; ++p) {
    float mv[4], xv[8];
    #pragma unroll
    for (int i = 0; i < 4; ++i) mv[i] = ms[kg + 16 * i][p];
    #pragma unroll
    for (int j = 0; j < 8; ++j) xv[j] = xs[cg + 16 * j][p];
    #pragma unroll
    for (int i = 0; i < 4; ++i)
      #pragma unroll
      for (int j = 0; j < 8; ++j) acc[i][j] = fmaf(mv[i], xv[j], acc[i][j]);
  }
  #pragma unroll
  for (int i = 0; i < 4; ++i)
    #pragma unroll
    for (int j = 0; j < 8; ++j)
      atomicAdd(&out_acc[((size_t)n * Kc + kg + 16 * i) * DIM + cg + 16 * j],
                acc[i][j]);
}

// ---------------------------------------------------------------- k_norm ----
__global__ __launch_bounds__(256) void k_norm(
    const float* __restrict__ out_acc, const float* __restrict__ cent,
    const float* __restrict__ S_part, float* __restrict__ out) {
  const int n = blockIdx.x;
  __shared__ float vals[Kc * DIM];
  __shared__ float Sk[Kc];
  __shared__ float kinv[Kc];
  __shared__ float red[4];
  if (threadIdx.x < Kc) {
    float s = 0.f;
    for (int t = 0; t < NT; ++t) s += S_part[((size_t)n * NT + t) * Kc + threadIdx.x];
    Sk[threadIdx.x] = s;
  }
  __syncthreads();
  for (int i = threadIdx.x; i < Kc * DIM; i += 256) {
    const int k = i >> 7, c = i & 127;
    vals[i] = out_acc[(size_t)n * Kc * DIM + i]
            - cent[(size_t)k * SP1 * DIM + c] * Sk[k];   // rep = centroids[:,0,:]
  }
  __syncthreads();
  {  // per-k L2 norm; rotated index -> 2-way banks instead of 64-way
    const int k = threadIdx.x >> 2, q = threadIdx.x & 3;
    float ss = 0.f;
    for (int cc = 0; cc < 32; ++cc) {
      const int c = q * 32 + ((cc + k + 8 * q) & 31);
      const float v = vals[k * DIM + c];
      ss = fmaf(v, v, ss);
    }
    ss += __shfl_xor(ss, 1, 64);
    ss += __shfl_xor(ss, 2, 64);
    if (q == 0) kinv[k] = 1.0f / fmaxf(sqrtf(ss), 1e-12f);
  }
  __syncthreads();
  float tp = 0.f;
  for (int i = threadIdx.x; i < Kc * DIM; i += 256) {
    const float v = vals[i] * kinv[i >> 7];
    vals[i] = v;
    tp = fmaf(v, v, tp);
  }
  #pragma unroll
  for (int off = 32; off > 0; off >>= 1) tp += __shfl_down(tp, off, 64);
  if ((threadIdx.x & 63) == 0) red[threadIdx.x >> 6] = tp;
  __syncthreads();
  const float rinv = 1.0f / fmaxf(sqrtf(red[0] + red[1] + red[2] + red[3]), 1e-12f);
  for (int i = threadIdx.x; i < Kc * DIM; i += 256)
    out[(size_t)n * Kc * DIM + i] = vals[i] * rinv;
}

// ----------------------------------------------------------------- launch ---
extern "C" void kernel_launch(void* const* d_in, const int* in_sizes, int n_in,
                              void* d_out, int out_size, void* d_ws, size_t ws_size,
                              hipStream_t stream) {
  const float* x    = (const float*)d_in[0];   // (16,128,30,40)
  const float* cent = (const float*)d_in[1];   // (64,5,128)
  float* out = (float*)d_out;                  // (16, 8192) f32

  // ws layout (floats): b[384] | S_part[16*19*64] | out_acc[131072] | mult[16*64*1200]
  float* b       = (float*)d_ws;
  float* S_part  = b + 384;
  float* out_acc = S_part + (size_t)Nn * NT * Kc;       // 19456
  float* mult_g  = out_acc + (size_t)Nn * Kc * DIM;     // 131072

  hipMemsetAsync(out_acc, 0, (size_t)Nn * Kc * DIM * sizeof(float), stream);
  k_bias<<<dim3(5), dim3(64), 0, stream>>>(cent, b);
  k_mult<<<dim3(NT, Nn), dim3(TPB2), 0, stream>>>(x, cent, b, mult_g, S_part);
  k_acc<<<dim3(NT, Nn), dim3(256), 0, stream>>>(x, mult_g, out_acc);
  k_norm<<<dim3(Nn), dim3(256), 0, stream>>>(out_acc, cent, S_part, out);
}

// Round 5
// 147.892 us; speedup vs baseline: 1.4194x; 1.4194x over previous
//
#include <hip/hip_runtime.h>
#include <math.h>

namespace {
constexpr int Kc   = 64;     // K
constexpr int SP1  = 5;      // S+1
constexpr int Mm   = Kc * SP1;          // 320
constexpr int DIM  = 128;
constexpr int Nn   = 16;
constexpr int Pp   = 1200;              // 30*40
constexpr int PT   = 64;                // pixels per tile
constexpr int NT   = (Pp + PT - 1) / PT;  // 19
constexpr int WAVES = 16;
constexpr int TPB2 = WAVES * 64;        // 1024
constexpr int KPW  = Kc / WAVES;        // 4 k-values per wave
}

// ---------------------------------------------------------------- k_bias ----
// one wave per centroid row m; lane c and c+64 -> shfl reduce
__global__ __launch_bounds__(256) void k_bias(const float* __restrict__ cent,
                                              float* __restrict__ b) {
  const int w = threadIdx.x >> 6, lane = threadIdx.x & 63;
  const int m = blockIdx.x * 4 + w;
  const float* r = cent + (size_t)m * DIM;
  float s = r[lane] * r[lane] + r[lane + 64] * r[lane + 64];
  #pragma unroll
  for (int off = 32; off > 0; off >>= 1) s += __shfl_down(s, off, 64);
  if (lane == 0) b[m] = -100.0f * sqrtf(s);   // -ALPHA * ||c||
}

// ---------------------------------------------------------------- k_mult ----
// 16 waves; lane = pixel (64/tile), wave w owns k in [w*4, w*4+4).
// x tile staged in LDS (shared by all waves); centroids via scalar loads.
__global__ __launch_bounds__(TPB2, 4) void k_mult(
    const float* __restrict__ x, const float* __restrict__ cent,
    const float* __restrict__ b, float* __restrict__ mult_g,
    float* __restrict__ S_part) {
  const int tile = blockIdx.x, n = blockIdx.y;
  const int p0   = tile * PT;
  const int lane = threadIdx.x & 63;
  const int w    = threadIdx.x >> 6;
  const int cnt  = min(PT, Pp - p0);
  const bool act = lane < cnt;

  __shared__ float xs[DIM][PT];          // 32 KB, c-major: xs[c][lane] 2-way free
  __shared__ float part[WAVES][SP1][PT]; // 20 KB, reused for M1 then Z1 partials
  __shared__ float m1f[SP1][PT];
  __shared__ float z1f[SP1][PT];

  // stage x[n,:,tile] -> LDS (coalesced: consecutive tid -> consecutive p)
  for (int i = threadIdx.x; i < DIM * PT; i += TPB2) {
    const int c = i >> 6, p = i & 63;
    xs[c][p] = (p < cnt) ? x[((size_t)n * DIM + c) * Pp + p0 + p] : 0.f;
  }
  __syncthreads();

  float cv[KPW][SP1];          // conv values, registers (all loops unrolled)
  float m1loc[SP1];
  #pragma unroll
  for (int s = 0; s < SP1; ++s) m1loc[s] = -3.4e38f;

  #pragma unroll
  for (int kk = 0; kk < KPW; ++kk) {
    const int k = __builtin_amdgcn_readfirstlane(w * KPW + kk);  // uniform -> s_load
    const float* wr = cent + (size_t)k * SP1 * DIM;
    const float* bb = b + k * SP1;
    float a0 = 0.f, a1 = 0.f, a2 = 0.f, a3 = 0.f, a4 = 0.f;
    #pragma unroll
    for (int c = 0; c < DIM; ++c) {
      const float xv = xs[c][lane];
      a0 = fmaf(wr[c],         xv, a0);
      a1 = fmaf(wr[DIM + c],   xv, a1);
      a2 = fmaf(wr[2*DIM + c], xv, a2);
      a3 = fmaf(wr[3*DIM + c], xv, a3);
      a4 = fmaf(wr[4*DIM + c], xv, a4);
    }
    const float t[SP1] = {a0, a1, a2, a3, a4};
    #pragma unroll
    for (int s = 0; s < SP1; ++s) {
      const float v = fmaf(200.0f, t[s], bb[s]);   // 2*ALPHA*dot + bias
      cv[kk][s] = v;
      m1loc[s] = fmaxf(m1loc[s], v);
    }
  }
  #pragma unroll
  for (int s = 0; s < SP1; ++s) part[w][s][lane] = m1loc[s];
  __syncthreads();
  // reduce M1 (max over k) across waves
  if (threadIdx.x < SP1 * PT) {
    const int s = threadIdx.x >> 6, l = threadIdx.x & 63;
    float m = part[0][s][l];
    #pragma unroll
    for (int ww = 1; ww < WAVES; ++ww) m = fmaxf(m, part[ww][s][l]);
    m1f[s][l] = m;
  }
  __syncthreads();
  float m1r[SP1];
  #pragma unroll
  for (int s = 0; s < SP1; ++s) m1r[s] = m1f[s][lane];
  // Z1 partials: sum_k exp(conv - M1[s])   (part[] safely reusable now)
  float z1loc[SP1] = {0.f, 0.f, 0.f, 0.f, 0.f};
  #pragma unroll
  for (int kk = 0; kk < KPW; ++kk) {
    #pragma unroll
    for (int s = 0; s < SP1; ++s) z1loc[s] += __expf(cv[kk][s] - m1r[s]);
  }
  #pragma unroll
  for (int s = 0; s < SP1; ++s) part[w][s][lane] = z1loc[s];
  __syncthreads();
  if (threadIdx.x < SP1 * PT) {
    const int s = threadIdx.x >> 6, l = threadIdx.x & 63;
    float z = part[0][s][l];
    #pragma unroll
    for (int ww = 1; ww < WAVES; ++ww) z += part[ww][s][l];
    z1f[s][l] = z;
  }
  __syncthreads();
  float z1r[SP1];
  #pragma unroll
  for (int s = 0; s < SP1; ++s) z1r[s] = z1f[s][lane];

  // mult = prod_s (1 + sm1*sm2),  sm1 = e1/Z1, sm2 = e2/Z2
  #pragma unroll
  for (int kk = 0; kk < KPW; ++kk) {
    const int k = w * KPW + kk;
    float M2 = cv[kk][0];
    #pragma unroll
    for (int s = 1; s < SP1; ++s) M2 = fmaxf(M2, cv[kk][s]);
    float e2[SP1], Z2 = 0.f;
    #pragma unroll
    for (int s = 0; s < SP1; ++s) { e2[s] = __expf(cv[kk][s] - M2); Z2 += e2[s]; }
    float mlt = 1.f;
    #pragma unroll
    for (int s = 0; s < SP1; ++s) {
      const float e1 = __expf(cv[kk][s] - m1r[s]);
      mlt *= 1.f + (e1 / z1r[s]) * (e2[s] / Z2);
    }
    if (act) mult_g[((size_t)n * Kc + k) * Pp + p0 + lane] = mlt;
    float msum = act ? mlt : 0.f;
    #pragma unroll
    for (int off = 32; off > 0; off >>= 1) msum += __shfl_down(msum, off, 64);
    if (lane == 0) S_part[((size_t)n * NT + tile) * Kc + k] = msum;  // deterministic
  }
}

// ----------------------------------------------------------------- k_acc ----
// out_acc[n,k,c] += sum_{p in chunk} x[n,c,p] * mult[n,k,p]
__global__ __launch_bounds__(512) void k_acc(
    const float* __restrict__ x, const float* __restrict__ mult_g,
    float* __restrict__ out_acc) {
  const int chunk = blockIdx.x, n = blockIdx.y;
  const int p0  = chunk * PT;
  const int cnt = min(PT, Pp - p0);
  __shared__ float xs[DIM][PT + 1];
  __shared__ float ms[Kc][PT + 1];
  for (int i = threadIdx.x; i < DIM * PT; i += 512) {
    const int c = i >> 6, p = i & 63;
    xs[c][p] = (p < cnt) ? x[((size_t)n * DIM + c) * Pp + p0 + p] : 0.f;
  }
  for (int i = threadIdx.x; i < Kc * PT; i += 512) {
    const int k = i >> 6, p = i & 63;
    ms[k][p] = (p < cnt) ? mult_g[((size_t)n * Kc + k) * Pp + p0 + p] : 0.f;
  }
  __syncthreads();
  // thread -> c = cg+16j (16 distinct banks, 4-lane broadcast),
  //           k = kg+32i (4 distinct rows/wave, 16-lane broadcast)
  const int cg = threadIdx.x & 15;
  const int kg = threadIdx.x >> 4;       // 0..31
  float acc[2][8] = {};
  for (int p = 0; p < PT; ++p) {
    float mv[2], xv[8];
    #pragma unroll
    for (int i = 0; i < 2; ++i) mv[i] = ms[kg + 32 * i][p];
    #pragma unroll
    for (int j = 0; j < 8; ++j) xv[j] = xs[cg + 16 * j][p];
    #pragma unroll
    for (int i = 0; i < 2; ++i)
      #pragma unroll
      for (int j = 0; j < 8; ++j) acc[i][j] = fmaf(mv[i], xv[j], acc[i][j]);
  }
  #pragma unroll
  for (int i = 0; i < 2; ++i)
    #pragma unroll
    for (int j = 0; j < 8; ++j)
      atomicAdd(&out_acc[((size_t)n * Kc + kg + 32 * i) * DIM + cg + 16 * j],
                acc[i][j]);
}

// ---------------------------------------------------------------- k_norm ----
// Per-k rows have L2-norm ~8000 >> eps, so after per-k normalization each row
// has norm exactly 1 (+/- f32 rounding ~1e-6) and the global norm over the 64
// concatenated unit rows is sqrt(64)=8. Fold the final /8 into the per-k
// scale; induced error <= ~3e-8 absolute (threshold 4.3e-4).
__global__ __launch_bounds__(256) void k_norm(
    const float* __restrict__ out_acc, const float* __restrict__ cent,
    const float* __restrict__ S_part, float* __restrict__ out) {
  const int n = blockIdx.y, k0 = blockIdx.x * 8;
  __shared__ float Sk[8];
  if (threadIdx.x < 8) {
    float s = 0.f;
    for (int t = 0; t < NT; ++t)
      s += S_part[((size_t)n * NT + t) * Kc + k0 + threadIdx.x];
    Sk[threadIdx.x] = s;
  }
  __syncthreads();
  const int kl = threadIdx.x >> 5;       // 0..7 (32-lane aligned groups)
  const int cl = threadIdx.x & 31;
  const int k  = k0 + kl;
  const float sk = Sk[kl];
  float v[4], ss = 0.f;
  #pragma unroll
  for (int j = 0; j < 4; ++j) {
    const int c = cl + 32 * j;
    v[j] = out_acc[((size_t)n * Kc + k) * DIM + c]
         - cent[(size_t)k * SP1 * DIM + c] * sk;   // rep = centroids[:,0,:]
    ss = fmaf(v[j], v[j], ss);
  }
  #pragma unroll
  for (int off = 16; off > 0; off >>= 1) ss += __shfl_xor(ss, off, 32);
  const float kinv = 0.125f / fmaxf(sqrtf(ss), 1e-12f);
  #pragma unroll
  for (int j = 0; j < 4; ++j)
    out[((size_t)n * Kc + k) * DIM + cl + 32 * j] = v[j] * kinv;
}

// ----------------------------------------------------------------- launch ---
extern "C" void kernel_launch(void* const* d_in, const int* in_sizes, int n_in,
                              void* d_out, int out_size, void* d_ws, size_t ws_size,
                              hipStream_t stream) {
  const float* x    = (const float*)d_in[0];   // (16,128,30,40)
  const float* cent = (const float*)d_in[1];   // (64,5,128)
  float* out = (float*)d_out;                  // (16, 8192) f32

  // ws layout (floats): b[384] | S_part[16*19*64] | out_acc[131072] | mult[16*64*1200]
  float* b       = (float*)d_ws;
  float* S_part  = b + 384;
  float* out_acc = S_part + (size_t)Nn * NT * Kc;       // 19456
  float* mult_g  = out_acc + (size_t)Nn * Kc * DIM;     // 131072

  hipMemsetAsync(out_acc, 0, (size_t)Nn * Kc * DIM * sizeof(float), stream);
  k_bias<<<dim3(Mm / 4), dim3(256), 0, stream>>>(cent, b);
  k_mult<<<dim3(NT, Nn), dim3(TPB2), 0, stream>>>(x, cent, b, mult_g, S_part);
  k_acc<<<dim3(NT, Nn), dim3(512), 0, stream>>>(x, mult_g, out_acc);
  k_norm<<<dim3(8, Nn), dim3(256), 0, stream>>>(out_acc, cent, S_part, out);
}

// Round 8
// 144.020 us; speedup vs baseline: 1.4576x; 1.0269x over previous
//
#include <hip/hip_runtime.h>
#include <math.h>

typedef _Float16 f16;
typedef unsigned short u16;
typedef unsigned int u32;
typedef f16 f16x8 __attribute__((ext_vector_type(8)));
typedef float f32x4 __attribute__((ext_vector_type(4)));

namespace {
constexpr int Kc  = 64;    // K
constexpr int SP1 = 5;     // S+1
constexpr int Mm  = Kc * SP1;   // 320
constexpr int DIM = 128;
constexpr int Nn  = 16;
constexpr int Pp  = 1200;
constexpr int PT  = 64;
constexpr int NT  = (Pp + PT - 1) / PT;   // 19
constexpr int WAVES = 16;
constexpr int TPB   = WAVES * 64;         // 1024
constexpr int KPW   = Kc / WAVES;         // 4

// k_fused dynamic-LDS offsets (bytes). Region A (OFF_A) is time-multiplexed:
//   phase 1: Ah[320][136] f16 (87040 B), then Al restaged over it
//   phase 2: convs f32[320][64] (81920 B)
//   phase 3: xpv f16[128][72] (18432 B)
constexpr int OFF_A    = 0;
constexpr int OFF_BH   = 87040;    // f16 [64][136] = 17408
constexpr int OFF_BL   = 104448;   // f16 [64][136] = 17408
constexpr int OFF_PART = 121856;   // f32 [16][5][64] = 20480
constexpr int OFF_M1F  = 142336;   // f32 [5][64] = 1280
constexpr int OFF_Z1F  = 143616;   // f32 [5][64] = 1280
constexpr int OFF_MS   = 144896;   // f16 [64][72] = 9216
constexpr int OFF_BS   = 154112;   // f32 [320] = 1280
constexpr int LDS_TOTAL = 155392;  // < 163840
}

// ---------------------------------------------------------------- k_bias ----
__global__ __launch_bounds__(256) void k_bias(const float* __restrict__ cent,
                                              float* __restrict__ b) {
  const int w = threadIdx.x >> 6, lane = threadIdx.x & 63;
  const int m = blockIdx.x * 4 + w;
  const float* r = cent + (size_t)m * DIM;
  float s = r[lane] * r[lane] + r[lane + 64] * r[lane + 64];
  #pragma unroll
  for (int off = 32; off > 0; off >>= 1) s += __shfl_down(s, off, 64);
  if (lane == 0) b[m] = -100.0f * sqrtf(s);
}

// ----------------------------------------------------------- k_prep_cent ----
// centroids (f32, [m=k*5+s][c]) -> f16 hi/lo, same layout
__global__ __launch_bounds__(1024) void k_prep_cent(
    const float* __restrict__ cent, u16* __restrict__ Ah, u16* __restrict__ Al) {
  const int i = blockIdx.x * 1024 + threadIdx.x;   // 40 blocks * 1024 = 40960
  const float v = cent[i];
  const f16 h  = (f16)v;
  const f16 lo = (f16)(v - (float)h);
  Ah[i] = __builtin_bit_cast(u16, h);
  Al[i] = __builtin_bit_cast(u16, lo);
}

// -------------------------------------------------------------- k_prep_x ----
// x[n][c][p] f32 -> xh_t/xl_t[n][p][c] f16 (transposed, c contiguous)
__global__ __launch_bounds__(256) void k_prep_x(
    const float* __restrict__ x, u16* __restrict__ xh_t, u16* __restrict__ xl_t) {
  const int tile = blockIdx.x, n = blockIdx.y;
  const int p0 = tile * PT, cnt = min(PT, Pp - p0);
  __shared__ float ls[PT][DIM + 1];
  for (int i = threadIdx.x; i < DIM * PT; i += 256) {
    const int c = i >> 6, p = i & 63;     // read coalesced in p
    ls[p][c] = (p < cnt) ? x[((size_t)n * DIM + c) * Pp + p0 + p] : 0.f;
  }
  __syncthreads();
  for (int i = threadIdx.x; i < PT * DIM; i += 256) {
    const int p = i >> 7, c = i & 127;    // write coalesced in c
    if (p < cnt) {
      const float v = ls[p][c];
      const f16 h  = (f16)v;
      const f16 lo = (f16)(v - (float)h);
      const size_t o = ((size_t)n * Pp + p0 + p) * DIM + c;
      xh_t[o] = __builtin_bit_cast(u16, h);
      xl_t[o] = __builtin_bit_cast(u16, lo);
    }
  }
}

// --------------------------------------------------------------- k_fused ----
// Per (n, 64-px tile): MFMA conv (f16 hi/lo 3-segment) -> softmax/mult ->
// MFMA PV (mult * x) -> atomicAdd partials into out_acc. 16 waves.
__global__ __launch_bounds__(TPB, 4) void k_fused(
    const float* __restrict__ x, const u16* __restrict__ Ah_g,
    const u16* __restrict__ Al_g, const u16* __restrict__ xh_t,
    const u16* __restrict__ xl_t, const float* __restrict__ b_g,
    float* __restrict__ out_acc, float* __restrict__ S_part) {
  const int tile = blockIdx.x, n = blockIdx.y;
  const int p0 = tile * PT, cnt = min(PT, Pp - p0);
  const int t = threadIdx.x, lane = t & 63, w = t >> 6;
  const int l15 = lane & 15, g = lane >> 4;   // MFMA lane decomposition
  const bool act = lane < cnt;

  extern __shared__ __align__(16) char smem[];
  f16*   Ablk   = (f16*)(smem + OFF_A);      // [320][136]
  f16*   Bh_s   = (f16*)(smem + OFF_BH);     // [64][136]  (x^T hi: [p][c])
  f16*   Bl_s   = (f16*)(smem + OFF_BL);     // [64][136]
  float* part   = (float*)(smem + OFF_PART); // [16][5][64]
  float* m1f    = (float*)(smem + OFF_M1F);  // [5][64]
  float* z1f    = (float*)(smem + OFF_Z1F);
  f16*   mult_s = (f16*)(smem + OFF_MS);     // [64][72]  ([k][p])
  float* b_s    = (float*)(smem + OFF_BS);   // [320]
  float* convs  = (float*)(smem + OFF_A);    // [320][64], aliases Ablk
  f16*   xpv    = (f16*)(smem + OFF_A);      // [128][72], aliases Ablk

  // ---- stage Ah (u32 = 2 f16), Bh, Bl, b ----
  for (int i2 = t; i2 < Mm * DIM / 2; i2 += TPB) {        // 20 iters
    const int m = i2 >> 6, c2 = i2 & 63;
    *(u32*)&Ablk[m * 136 + c2 * 2] = ((const u32*)Ah_g)[i2];
  }
  for (int i2 = t; i2 < PT * DIM / 2; i2 += TPB) {        // 4 iters each
    const int p = i2 >> 6, c2 = i2 & 63;
    const u32 vh = (p < cnt) ? ((const u32*)xh_t)[((size_t)n * Pp + p0 + p) * 64 + c2] : 0u;
    const u32 vl = (p < cnt) ? ((const u32*)xl_t)[((size_t)n * Pp + p0 + p) * 64 + c2] : 0u;
    *(u32*)&Bh_s[p * 136 + c2 * 2] = vh;
    *(u32*)&Bl_s[p * 136 + c2 * 2] = vl;
  }
  if (t < Mm) b_s[t] = b_g[t];
  __syncthreads();

  // ---- MFMA conv: wave (wm,wp): m-range wm*80 (5 tiles), p-tile wp*16 ----
  const int wm = w >> 2, wp = w & 3;
  const int m0 = wm * 80;
  f32x4 acc[5];
  #pragma unroll
  for (int i = 0; i < 5; ++i) acc[i] = (f32x4){0.f, 0.f, 0.f, 0.f};

  #pragma unroll
  for (int seg = 0; seg < 3; ++seg) {
    if (seg == 2) {  // restage Al over Ah
      __syncthreads();
      for (int i2 = t; i2 < Mm * DIM / 2; i2 += TPB) {
        const int m = i2 >> 6, c2 = i2 & 63;
        *(u32*)&Ablk[m * 136 + c2 * 2] = ((const u32*)Al_g)[i2];
      }
      __syncthreads();
    }
    const f16* Bseg = (seg == 1) ? Bl_s : Bh_s;
    #pragma unroll
    for (int kc = 0; kc < 4; ++kc) {
      const f16x8 bf = *(const f16x8*)&Bseg[(wp * 16 + l15) * 136 + kc * 32 + g * 8];
      #pragma unroll
      for (int t5 = 0; t5 < 5; ++t5) {
        const f16x8 af = *(const f16x8*)&Ablk[(m0 + t5 * 16 + l15) * 136 + kc * 32 + g * 8];
        acc[t5] = __builtin_amdgcn_mfma_f32_16x16x32_f16(af, bf, acc[t5], 0, 0, 0);
      }
    }
  }
  __syncthreads();   // all MFMA reads of Ablk done

  // ---- epilogue: conv = 200*dot + b  ->  convs[m][p] (aliases Ablk) ----
  const int pcol = wp * 16 + l15;
  #pragma unroll
  for (int t5 = 0; t5 < 5; ++t5)
    #pragma unroll
    for (int r = 0; r < 4; ++r) {
      const int m = m0 + t5 * 16 + g * 4 + r;     // C/D: row=(lane>>4)*4+reg, col=lane&15
      convs[m * 64 + pcol] = fmaf(200.0f, acc[t5][r], b_s[m]);
    }
  __syncthreads();

  // ---- softmax phase (round-5 proven structure; lane=pixel, KPW=4) ----
  float cv[KPW][SP1];
  float m1loc[SP1];
  #pragma unroll
  for (int s = 0; s < SP1; ++s) m1loc[s] = -3.4e38f;
  #pragma unroll
  for (int kk = 0; kk < KPW; ++kk)
    #pragma unroll
    for (int s = 0; s < SP1; ++s) {
      const float v = convs[((w * KPW + kk) * SP1 + s) * 64 + lane];
      cv[kk][s] = v;
      m1loc[s] = fmaxf(m1loc[s], v);
    }
  __syncthreads();   // everyone's cv read; convs region now dead

  // stage xpv[c][p] = f16(x) over the dead convs region (read before PV barrier)
  for (int i = t; i < DIM * PT; i += TPB) {
    const int c = i >> 6, p = i & 63;
    const float v = (p < cnt) ? x[((size_t)n * DIM + c) * Pp + p0 + p] : 0.f;
    xpv[c * 72 + p] = (f16)v;
  }

  #pragma unroll
  for (int s = 0; s < SP1; ++s) part[(w * SP1 + s) * 64 + lane] = m1loc[s];
  __syncthreads();
  if (t < SP1 * 64) {
    const int s = t >> 6, l = t & 63;
    float m = part[s * 64 + l];
    #pragma unroll
    for (int ww = 1; ww < WAVES; ++ww) m = fmaxf(m, part[(ww * SP1 + s) * 64 + l]);
    m1f[s * 64 + l] = m;
  }
  __syncthreads();
  float m1r[SP1];
  #pragma unroll
  for (int s = 0; s < SP1; ++s) m1r[s] = m1f[s * 64 + lane];
  float z1loc[SP1] = {0.f, 0.f, 0.f, 0.f, 0.f};
  #pragma unroll
  for (int kk = 0; kk < KPW; ++kk)
    #pragma unroll
    for (int s = 0; s < SP1; ++s) z1loc[s] += __expf(cv[kk][s] - m1r[s]);
  #pragma unroll
  for (int s = 0; s < SP1; ++s) part[(w * SP1 + s) * 64 + lane] = z1loc[s];
  __syncthreads();
  if (t < SP1 * 64) {
    const int s = t >> 6, l = t & 63;
    float z = part[s * 64 + l];
    #pragma unroll
    for (int ww = 1; ww < WAVES; ++ww) z += part[(ww * SP1 + s) * 64 + l];
    z1f[s * 64 + l] = z;
  }
  __syncthreads();
  float z1r[SP1];
  #pragma unroll
  for (int s = 0; s < SP1; ++s) z1r[s] = z1f[s * 64 + lane];

  #pragma unroll
  for (int kk = 0; kk < KPW; ++kk) {
    const int k = w * KPW + kk;
    float M2 = cv[kk][0];
    #pragma unroll
    for (int s = 1; s < SP1; ++s) M2 = fmaxf(M2, cv[kk][s]);
    float e2[SP1], Z2 = 0.f;
    #pragma unroll
    for (int s = 0; s < SP1; ++s) { e2[s] = __expf(cv[kk][s] - M2); Z2 += e2[s]; }
    float mlt = 1.f;
    #pragma unroll
    for (int s = 0; s < SP1; ++s) {
      const float e1 = __expf(cv[kk][s] - m1r[s]);
      mlt *= 1.f + (e1 / z1r[s]) * (e2[s] / Z2);
    }
    mult_s[k * 72 + lane] = act ? (f16)mlt : (f16)0.f;   // masked for PV
    float msum = act ? mlt : 0.f;
    #pragma unroll
    for (int off = 32; off > 0; off >>= 1) msum += __shfl_down(msum, off, 64);
    if (lane == 0) S_part[((size_t)n * NT + tile) * Kc + k] = msum;
  }
  __syncthreads();   // mult_s + xpv complete

  // ---- PV MFMA: D[k][c] = sum_p mult[k][p] * xh[c][p]; atomic into out_acc ----
  const int wm2 = w & 3;          // k-tile 0..3
  const int wn2 = (w >> 2) * 2;   // c-tiles {wn2, wn2+1}
  f32x4 acc2[2];
  acc2[0] = (f32x4){0.f, 0.f, 0.f, 0.f};
  acc2[1] = (f32x4){0.f, 0.f, 0.f, 0.f};
  #pragma unroll
  for (int kc = 0; kc < 2; ++kc) {
    const f16x8 am = *(const f16x8*)&mult_s[(wm2 * 16 + l15) * 72 + kc * 32 + g * 8];
    #pragma unroll
    for (int tn = 0; tn < 2; ++tn) {
      const f16x8 bx = *(const f16x8*)&xpv[((wn2 + tn) * 16 + l15) * 72 + kc * 32 + g * 8];
      acc2[tn] = __builtin_amdgcn_mfma_f32_16x16x32_f16(am, bx, acc2[tn], 0, 0, 0);
    }
  }
  #pragma unroll
  for (int tn = 0; tn < 2; ++tn)
    #pragma unroll
    for (int r = 0; r < 4; ++r) {
      const int k = wm2 * 16 + g * 4 + r;
      const int c = (wn2 + tn) * 16 + l15;
      atomicAdd(&out_acc[((size_t)n * Kc + k) * DIM + c], acc2[tn][r]);
    }
}

// ---------------------------------------------------------------- k_norm ----
__global__ __launch_bounds__(256) void k_norm(
    const float* __restrict__ out_acc, const float* __restrict__ cent,
    const float* __restrict__ S_part, float* __restrict__ out) {
  const int n = blockIdx.y, k0 = blockIdx.x * 8;
  __shared__ float Sk[8];
  if (threadIdx.x < 8) {
    float s = 0.f;
    for (int tt = 0; tt < NT; ++tt)
      s += S_part[((size_t)n * NT + tt) * Kc + k0 + threadIdx.x];
    Sk[threadIdx.x] = s;
  }
  __syncthreads();
  const int kl = threadIdx.x >> 5, cl = threadIdx.x & 31;
  const int k = k0 + kl;
  const float sk = Sk[kl];
  float v[4], ss = 0.f;
  #pragma unroll
  for (int j = 0; j < 4; ++j) {
    const int c = cl + 32 * j;
    v[j] = out_acc[((size_t)n * Kc + k) * DIM + c]
         - cent[(size_t)k * SP1 * DIM + c] * sk;
    ss = fmaf(v[j], v[j], ss);
  }
  #pragma unroll
  for (int off = 16; off > 0; off >>= 1) ss += __shfl_xor(ss, off, 32);
  const float kinv = 0.125f / fmaxf(sqrtf(ss), 1e-12f);  // global norm = 8 analytically
  #pragma unroll
  for (int j = 0; j < 4; ++j)
    out[((size_t)n * Kc + k) * DIM + cl + 32 * j] = v[j] * kinv;
}

// ----------------------------------------------------------------- launch ---
extern "C" void kernel_launch(void* const* d_in, const int* in_sizes, int n_in,
                              void* d_out, int out_size, void* d_ws, size_t ws_size,
                              hipStream_t stream) {
  const float* x    = (const float*)d_in[0];   // (16,128,30,40)
  const float* cent = (const float*)d_in[1];   // (64,5,128)
  float* out = (float*)d_out;

  // ws: f32 b[384] | S_part[19456] | out_acc[131072] | u16 Ah[40960] Al[40960]
  //     xh_t[2457600] xl_t[2457600]   (total ~10.6 MB)
  float* b       = (float*)d_ws;
  float* S_part  = b + 384;
  float* out_acc = S_part + (size_t)Nn * NT * Kc;
  u16* Ah_g = (u16*)(out_acc + (size_t)Nn * Kc * DIM);
  u16* Al_g = Ah_g + (size_t)Mm * DIM;
  u16* xh_t = Al_g + (size_t)Mm * DIM;
  u16* xl_t = xh_t + (size_t)Nn * Pp * DIM;

  hipMemsetAsync(out_acc, 0, (size_t)Nn * Kc * DIM * sizeof(float), stream);
  k_bias<<<dim3(Mm / 4), dim3(256), 0, stream>>>(cent, b);
  k_prep_cent<<<dim3(Mm * DIM / 1024), dim3(1024), 0, stream>>>(cent, Ah_g, Al_g);
  k_prep_x<<<dim3(NT, Nn), dim3(256), 0, stream>>>(x, xh_t, xl_t);
  k_fused<<<dim3(NT, Nn), dim3(TPB), LDS_TOTAL, stream>>>(
      x, Ah_g, Al_g, xh_t, xl_t, b, out_acc, S_part);
  k_norm<<<dim3(8, Nn), dim3(256), 0, stream>>>(out_acc, cent, S_part, out);
}

// Round 9
// 117.041 us; speedup vs baseline: 1.7936x; 1.2305x over previous
//
#include <hip/hip_runtime.h>
#include <math.h>

typedef _Float16 f16;
typedef unsigned short u16;
typedef unsigned int u32;
typedef f16 f16x8 __attribute__((ext_vector_type(8)));
typedef float f32x4 __attribute__((ext_vector_type(4)));

namespace {
constexpr int Kc  = 64;    // K
constexpr int SP1 = 5;     // S+1
constexpr int Mm  = Kc * SP1;   // 320
constexpr int DIM = 128;
constexpr int Nn  = 16;
constexpr int Pp  = 1200;
constexpr int PT  = 64;
constexpr int NT  = (Pp + PT - 1) / PT;   // 19
constexpr int WAVES = 16;
constexpr int TPB   = WAVES * 64;         // 1024
constexpr int KPW   = Kc / WAVES;         // 4

// k_fused LDS (bytes). Region A is time-multiplexed:
//   Ah[320][136] f16 (87040) -> Al restaged -> convs f32[320][64] (81920)
//   -> xpv f16[128][72] (18432).
// Region [OFF_PART..TOTAL) holds x-f32 scratch [64][129] (33024) during
// staging; later part/m1f/z1f/ms/bs (b_s written only after scratch dies).
constexpr int OFF_A    = 0;
constexpr int OFF_BH   = 87040;    // f16 [64][136] = 17408
constexpr int OFF_BL   = 104448;   // f16 [64][136] = 17408
constexpr int OFF_PART = 121856;   // f32 [16][5][64] = 20480
constexpr int OFF_M1F  = 142336;   // f32 [5][64] = 1280
constexpr int OFF_Z1F  = 143616;   // f32 [5][64] = 1280
constexpr int OFF_MS   = 144896;   // f16 [64][72] = 9216
constexpr int OFF_BS   = 154112;   // f32 [320] = 1280
constexpr int LDS_TOTAL = 155392;  // < 163840
}

// ----------------------------------------------------------------- k_prep ---
// wave w of block b handles centroid row m = b*16+w:
// bias b[m] = -100*||row||  AND  f16 hi/lo split -> Ah/Al.
__global__ __launch_bounds__(1024) void k_prep(
    const float* __restrict__ cent, float* __restrict__ b,
    u16* __restrict__ Ah, u16* __restrict__ Al) {
  const int w = threadIdx.x >> 6, lane = threadIdx.x & 63;
  const int m = blockIdx.x * 16 + w;
  const float v0 = cent[(size_t)m * DIM + lane];
  const float v1 = cent[(size_t)m * DIM + 64 + lane];
  float s = v0 * v0 + v1 * v1;
  #pragma unroll
  for (int off = 32; off > 0; off >>= 1) s += __shfl_down(s, off, 64);
  if (lane == 0) b[m] = -100.0f * sqrtf(s);   // -ALPHA * ||c||
  const f16 h0 = (f16)v0, h1 = (f16)v1;
  Ah[(size_t)m * DIM + lane]      = __builtin_bit_cast(u16, h0);
  Ah[(size_t)m * DIM + 64 + lane] = __builtin_bit_cast(u16, h1);
  Al[(size_t)m * DIM + lane]      = __builtin_bit_cast(u16, (f16)(v0 - (float)h0));
  Al[(size_t)m * DIM + 64 + lane] = __builtin_bit_cast(u16, (f16)(v1 - (float)h1));
}

// --------------------------------------------------------------- k_fused ----
// Per (n, 64-px tile): stage x f32 -> split hi/lo in-kernel -> MFMA conv
// (3-segment f16 hi/lo) -> softmax/mult -> PV MFMA -> DETERMINISTIC partial
// store to out_part[n][tile] (no atomics).
__global__ __launch_bounds__(TPB, 4) void k_fused(
    const float* __restrict__ x, const u16* __restrict__ Ah_g,
    const u16* __restrict__ Al_g, const float* __restrict__ b_g,
    float* __restrict__ out_part, float* __restrict__ S_part) {
  const int tile = blockIdx.x, n = blockIdx.y;
  const int p0 = tile * PT, cnt = min(PT, Pp - p0);
  const int t = threadIdx.x, lane = t & 63, w = t >> 6;
  const int l15 = lane & 15, g = lane >> 4;   // MFMA lane decomposition
  const bool act = lane < cnt;

  extern __shared__ __align__(16) char smem[];
  f16*   Ablk    = (f16*)(smem + OFF_A);
  u32*   Ablk32  = (u32*)(smem + OFF_A);
  f16*   Bh_s    = (f16*)(smem + OFF_BH);     // x^T hi [p][c]
  u32*   Bh32    = (u32*)(smem + OFF_BH);
  f16*   Bl_s    = (f16*)(smem + OFF_BL);
  u32*   Bl32    = (u32*)(smem + OFF_BL);
  float* part    = (float*)(smem + OFF_PART);
  float* scratch = (float*)(smem + OFF_PART); // [64][129] f32, staging only
  float* m1f     = (float*)(smem + OFF_M1F);
  float* z1f     = (float*)(smem + OFF_Z1F);
  f16*   mult_s  = (f16*)(smem + OFF_MS);     // [64][72] ([k][p])
  float* b_s     = (float*)(smem + OFF_BS);
  float* convs   = (float*)(smem + OFF_A);    // [320][64], aliases Ablk
  u16*   xpv     = (u16*)(smem + OFF_A);      // [128][72], aliases Ablk

  // ---- phase 0: Ah -> LDS ; x f32 -> scratch [p][c] ----
  for (int i2 = t; i2 < Mm * DIM / 2; i2 += TPB) {        // 20 iters
    const int m = i2 >> 6, c2 = i2 & 63;
    Ablk32[m * 68 + c2] = ((const u32*)Ah_g)[i2];
  }
  for (int i = t; i < DIM * PT; i += TPB) {               // 8 iters, coalesced in p
    const int c = i >> 6, p = i & 63;
    scratch[p * 129 + c] = (p < cnt) ? x[((size_t)n * DIM + c) * Pp + p0 + p] : 0.f;
  }
  __syncthreads();

  // ---- phase 0.5: in-kernel f16 hi/lo split -> Bh, Bl ----
  for (int i = t; i < PT * 64; i += TPB) {                // 4 iters
    const int p = i >> 6, c2 = i & 63;
    const float v0 = scratch[p * 129 + 2 * c2];
    const float v1 = scratch[p * 129 + 2 * c2 + 1];
    const f16 h0 = (f16)v0, h1 = (f16)v1;
    const f16 l0 = (f16)(v0 - (float)h0), l1 = (f16)(v1 - (float)h1);
    Bh32[p * 68 + c2] = (u32)__builtin_bit_cast(u16, h0) |
                        ((u32)__builtin_bit_cast(u16, h1) << 16);
    Bl32[p * 68 + c2] = (u32)__builtin_bit_cast(u16, l0) |
                        ((u32)__builtin_bit_cast(u16, l1) << 16);
  }
  __syncthreads();   // scratch dead from here on

  // ---- MFMA conv: wave (wm,wp): m-range wm*80 (5 tiles), p-tile wp*16 ----
  const int wm = w >> 2, wp = w & 3;
  const int m0 = wm * 80;
  f32x4 acc[5];
  #pragma unroll
  for (int i = 0; i < 5; ++i) acc[i] = (f32x4){0.f, 0.f, 0.f, 0.f};

  #pragma unroll
  for (int seg = 0; seg < 3; ++seg) {
    if (seg == 2) {  // restage Al over Ah; stage b_s (scratch long dead)
      __syncthreads();
      for (int i2 = t; i2 < Mm * DIM / 2; i2 += TPB) {
        const int m = i2 >> 6, c2 = i2 & 63;
        Ablk32[m * 68 + c2] = ((const u32*)Al_g)[i2];
      }
      if (t < Mm) b_s[t] = b_g[t];
      __syncthreads();
    }
    const f16* Bseg = (seg == 1) ? Bl_s : Bh_s;
    #pragma unroll
    for (int kc = 0; kc < 4; ++kc) {
      const f16x8 bf = *(const f16x8*)&Bseg[(wp * 16 + l15) * 136 + kc * 32 + g * 8];
      #pragma unroll
      for (int t5 = 0; t5 < 5; ++t5) {
        const f16x8 af = *(const f16x8*)&Ablk[(m0 + t5 * 16 + l15) * 136 + kc * 32 + g * 8];
        acc[t5] = __builtin_amdgcn_mfma_f32_16x16x32_f16(af, bf, acc[t5], 0, 0, 0);
      }
    }
  }
  __syncthreads();   // all MFMA reads of Ablk done

  // ---- epilogue: conv = 200*dot + b -> convs[m][p] (aliases Ablk) ----
  const int pcol = wp * 16 + l15;
  #pragma unroll
  for (int t5 = 0; t5 < 5; ++t5)
    #pragma unroll
    for (int r = 0; r < 4; ++r) {
      const int m = m0 + t5 * 16 + g * 4 + r;   // C/D: row=(lane>>4)*4+reg, col=lane&15
      convs[m * 64 + pcol] = fmaf(200.0f, acc[t5][r], b_s[m]);
    }
  __syncthreads();

  // ---- softmax (lane = pixel, wave owns 4 k) ----
  float cv[KPW][SP1];
  float m1loc[SP1];
  #pragma unroll
  for (int s = 0; s < SP1; ++s) m1loc[s] = -3.4e38f;
  #pragma unroll
  for (int kk = 0; kk < KPW; ++kk)
    #pragma unroll
    for (int s = 0; s < SP1; ++s) {
      const float v = convs[((w * KPW + kk) * SP1 + s) * 64 + lane];
      cv[kk][s] = v;
      m1loc[s] = fmaxf(m1loc[s], v);
    }
  __syncthreads();   // everyone's cv read; convs region dead

  // xpv[c][p] = f16(x) -- transpose from Bh_s (no HBM): xh IS (f16)x
  for (int i = t; i < DIM * PT; i += TPB) {
    const int c = i >> 6, p = i & 63;
    xpv[c * 72 + p] = ((const u16*)Bh_s)[p * 136 + c];
  }

  #pragma unroll
  for (int s = 0; s < SP1; ++s) part[(w * SP1 + s) * 64 + lane] = m1loc[s];
  __syncthreads();
  if (t < SP1 * 64) {
    const int s = t >> 6, l = t & 63;
    float m = part[s * 64 + l];
    #pragma unroll
    for (int ww = 1; ww < WAVES; ++ww) m = fmaxf(m, part[(ww * SP1 + s) * 64 + l]);
    m1f[s * 64 + l] = m;
  }
  __syncthreads();
  float m1r[SP1];
  #pragma unroll
  for (int s = 0; s < SP1; ++s) m1r[s] = m1f[s * 64 + lane];
  float z1loc[SP1] = {0.f, 0.f, 0.f, 0.f, 0.f};
  #pragma unroll
  for (int kk = 0; kk < KPW; ++kk)
    #pragma unroll
    for (int s = 0; s < SP1; ++s) z1loc[s] += __expf(cv[kk][s] - m1r[s]);
  #pragma unroll
  for (int s = 0; s < SP1; ++s) part[(w * SP1 + s) * 64 + lane] = z1loc[s];
  __syncthreads();
  if (t < SP1 * 64) {
    const int s = t >> 6, l = t & 63;
    float z = part[s * 64 + l];
    #pragma unroll
    for (int ww = 1; ww < WAVES; ++ww) z += part[(ww * SP1 + s) * 64 + l];
    z1f[s * 64 + l] = z;
  }
  __syncthreads();
  float z1r[SP1];
  #pragma unroll
  for (int s = 0; s < SP1; ++s) z1r[s] = z1f[s * 64 + lane];

  #pragma unroll
  for (int kk = 0; kk < KPW; ++kk) {
    const int k = w * KPW + kk;
    float M2 = cv[kk][0];
    #pragma unroll
    for (int s = 1; s < SP1; ++s) M2 = fmaxf(M2, cv[kk][s]);
    float e2[SP1], Z2 = 0.f;
    #pragma unroll
    for (int s = 0; s < SP1; ++s) { e2[s] = __expf(cv[kk][s] - M2); Z2 += e2[s]; }
    float mlt = 1.f;
    #pragma unroll
    for (int s = 0; s < SP1; ++s) {
      const float e1 = __expf(cv[kk][s] - m1r[s]);
      mlt *= 1.f + (e1 / z1r[s]) * (e2[s] / Z2);
    }
    mult_s[k * 72 + lane] = act ? (f16)mlt : (f16)0.f;   // masked for PV
    float msum = act ? mlt : 0.f;
    #pragma unroll
    for (int off = 32; off > 0; off >>= 1) msum += __shfl_down(msum, off, 64);
    if (lane == 0) S_part[((size_t)n * NT + tile) * Kc + k] = msum;
  }
  __syncthreads();   // mult_s + xpv complete

  // ---- PV MFMA: D[k][c] = sum_p mult[k][p]*xh[c][p]; plain stores ----
  const int wm2 = w & 3;          // k-tile 0..3
  const int wn2 = (w >> 2) * 2;   // c-tiles {wn2, wn2+1}
  f32x4 acc2[2];
  acc2[0] = (f32x4){0.f, 0.f, 0.f, 0.f};
  acc2[1] = (f32x4){0.f, 0.f, 0.f, 0.f};
  #pragma unroll
  for (int kc = 0; kc < 2; ++kc) {
    const f16x8 am = *(const f16x8*)&mult_s[(wm2 * 16 + l15) * 72 + kc * 32 + g * 8];
    #pragma unroll
    for (int tn = 0; tn < 2; ++tn) {
      const f16x8 bx = *(const f16x8*)((const f16*)xpv + ((wn2 + tn) * 16 + l15) * 72 + kc * 32 + g * 8);
      acc2[tn] = __builtin_amdgcn_mfma_f32_16x16x32_f16(am, bx, acc2[tn], 0, 0, 0);
    }
  }
  float* dst = out_part + ((size_t)(n * NT + tile) * Kc) * DIM;
  #pragma unroll
  for (int tn = 0; tn < 2; ++tn)
    #pragma unroll
    for (int r = 0; r < 4; ++r)
      dst[(wm2 * 16 + g * 4 + r) * DIM + (wn2 + tn) * 16 + l15] = acc2[tn][r];
}

// ---------------------------------------------------------------- k_norm ----
// Reduce 19 tile-partials, subtract rep*S, per-k normalize; global norm = 8
// analytically (per-k rows are unit vectors; see round-5 derivation).
__global__ __launch_bounds__(256) void k_norm(
    const float* __restrict__ out_part, const float* __restrict__ cent,
    const float* __restrict__ S_part, float* __restrict__ out) {
  const int n = blockIdx.y, k0 = blockIdx.x * 4;
  __shared__ float Sk[4];
  if (threadIdx.x < 4) {
    float s = 0.f;
    for (int tt = 0; tt < NT; ++tt)
      s += S_part[((size_t)n * NT + tt) * Kc + k0 + threadIdx.x];
    Sk[threadIdx.x] = s;
  }
  __syncthreads();
  const int kl = threadIdx.x >> 6, cl = threadIdx.x & 63;
  const int k = k0 + kl;
  const float sk = Sk[kl];
  float v[2], ss = 0.f;
  #pragma unroll
  for (int j = 0; j < 2; ++j) {
    const int c = cl + 64 * j;
    float a = 0.f;
    for (int tt = 0; tt < NT; ++tt)
      a += out_part[(((size_t)n * NT + tt) * Kc + k) * DIM + c];
    v[j] = a - cent[(size_t)k * SP1 * DIM + c] * sk;   // rep = centroids[:,0,:]
    ss = fmaf(v[j], v[j], ss);
  }
  #pragma unroll
  for (int off = 32; off > 0; off >>= 1) ss += __shfl_xor(ss, off, 64);
  const float kinv = 0.125f / fmaxf(sqrtf(ss), 1e-12f);
  #pragma unroll
  for (int j = 0; j < 2; ++j)
    out[((size_t)n * Kc + k) * DIM + cl + 64 * j] = v[j] * kinv;
}

// ----------------------------------------------------------------- launch ---
extern "C" void kernel_launch(void* const* d_in, const int* in_sizes, int n_in,
                              void* d_out, int out_size, void* d_ws, size_t ws_size,
                              hipStream_t stream) {
  const float* x    = (const float*)d_in[0];   // (16,128,30,40)
  const float* cent = (const float*)d_in[1];   // (64,5,128)
  float* out = (float*)d_out;

  // ws (floats): b[384] | S_part[16*19*64] | out_part[16*19*64*128]
  // then u16: Ah[40960] | Al[40960].  ~10.2 MB, all fully written (no memset).
  float* b        = (float*)d_ws;
  float* S_part   = b + 384;
  float* out_part = S_part + (size_t)Nn * NT * Kc;
  u16* Ah_g = (u16*)(out_part + (size_t)Nn * NT * Kc * DIM);
  u16* Al_g = Ah_g + (size_t)Mm * DIM;

  k_prep<<<dim3(Mm / 16), dim3(1024), 0, stream>>>(cent, b, Ah_g, Al_g);
  k_fused<<<dim3(NT, Nn), dim3(TPB), LDS_TOTAL, stream>>>(
      x, Ah_g, Al_g, b, out_part, S_part);
  k_norm<<<dim3(Kc / 4, Nn), dim3(256), 0, stream>>>(out_part, cent, S_part, out);
}